// Round 3
// baseline (347.541 us; speedup 1.0000x reference)
//
#include <hip/hip_runtime.h>

// ---------- constants for this problem ----------
// B=4, N=2048, C=1024, H=16, D=64; M = B*N = 8192
#define MM   8192
#define CC   1024
#define F3   3072
#define NN   2048
#define HH   16
#define DD   64
// q scale: D^-0.5 * log2(e), folded into q during RoPE so softmax uses exp2
#define QSCALE 0.1803368801111731f

typedef __attribute__((ext_vector_type(8))) __bf16 bf16x8;
typedef __attribute__((ext_vector_type(4))) float floatx4;
typedef __attribute__((ext_vector_type(4))) unsigned uintx4;

__device__ __forceinline__ unsigned short f2b(float f) {
  union { float f; unsigned int u; } v; v.f = f;
  unsigned int r = v.u + 0x7fffu + ((v.u >> 16) & 1u);
  return (unsigned short)(r >> 16);
}
__device__ __forceinline__ float b2f(unsigned short b) {
  union { unsigned int u; float f; } v; v.u = ((unsigned int)b) << 16;
  return v.f;
}

// async global->LDS, 16B per lane. LDS dest is wave-uniform base + lane*16,
// so the LDS layout must be lane-linear (no padding) in chunk order.
__device__ __forceinline__ void gl_lds16(const unsigned short* g, unsigned short* l) {
  __builtin_amdgcn_global_load_lds((const __attribute__((address_space(1))) void*)g,
                                   (__attribute__((address_space(3))) void*)l, 16, 0, 0);
}

// ---------- fp32 -> bf16 conversion (vectorized x4) ----------
__global__ __launch_bounds__(256) void f32_to_bf16_k(const float* __restrict__ in,
                                                     unsigned short* __restrict__ out, int n4) {
  int i = blockIdx.x * 256 + threadIdx.x;
  if (i < n4) {
    float4 v = ((const float4*)in)[i];
    ushort4 o;
    o.x = f2b(v.x); o.y = f2b(v.y); o.z = f2b(v.z); o.w = f2b(v.w);
    ((ushort4*)out)[i] = o;
  }
}

// ---------- GEMM: A[M,K] bf16 row-major  x  Bm[F,K] bf16 row-major (B^T layout) ----------
// 128x128 tile, 4 waves (2x2 of 64x64), 16x16x32 bf16 MFMA, BK=32.
// ROPE=true (GEMM1): each wave's 64-col slice is one head; the RoPE pair
// (d, d+32) is acc[im][jf] / acc[im][jf+2] in the SAME lane -> rotate in
// registers on fp32 accumulators, wave-uniform branch on head<32, q scaled.
template <int F, bool BF16OUT, bool ROPE>
__global__ __launch_bounds__(256) void gemm_bt(const unsigned short* __restrict__ A,
                                               const unsigned short* __restrict__ Bm,
                                               void* __restrict__ Cout,
                                               const float* __restrict__ bias,
                                               const float* __restrict__ rcp,
                                               const float* __restrict__ spp, int K) {
  __shared__ alignas(16) unsigned short lA[128 * 32];
  __shared__ alignas(16) unsigned short lB[128 * 32];
  const int tid = threadIdx.x, lane = tid & 63, wave = tid >> 6;
  const int r16 = lane & 15, q4 = lane >> 4;
  const int rowBase = blockIdx.x * 128, colBase = blockIdx.y * 128;
  const int wm = wave & 1, wf = wave >> 1;

  floatx4 acc[4][4];
  const floatx4 z = {0.f, 0.f, 0.f, 0.f};
  for (int i = 0; i < 4; ++i)
    for (int j = 0; j < 4; ++j) acc[i][j] = z;

  for (int k0 = 0; k0 < K; k0 += 32) {
    __syncthreads();
#pragma unroll
    for (int i = 0; i < 2; ++i) {
      int chunk = i * 256 + tid;            // 0..511, 16B each; LDS off = chunk*16B
      int row = chunk >> 2, col = (chunk & 3) * 8;
      gl_lds16(A + (size_t)(rowBase + row) * K + k0 + col, &lA[chunk * 8]);
      gl_lds16(Bm + (size_t)(colBase + row) * K + k0 + col, &lB[chunk * 8]);
    }
    __syncthreads();
    bf16x8 af[4];
    for (int im = 0; im < 4; ++im)
      af[im] = *(const bf16x8*)(&lA[(wm * 64 + im * 16 + r16) * 32 + q4 * 8]);
    for (int jf = 0; jf < 4; ++jf) {
      bf16x8 bfr = *(const bf16x8*)(&lB[(wf * 64 + jf * 16 + r16) * 32 + q4 * 8]);
      for (int im = 0; im < 4; ++im)
        acc[im][jf] = __builtin_amdgcn_mfma_f32_16x16x32_bf16(af[im], bfr, acc[im][jf], 0, 0, 0);
    }
  }

  if (ROPE) {
    int head = (colBase >> 6) + wf;          // 0..47; q:0-15, k:16-31, v:32-47
    if (head < 32) {
      const bool isq = head < 16;
      for (int im = 0; im < 4; ++im)
        for (int jf = 0; jf < 2; ++jf)
          for (int r = 0; r < 4; ++r) {
            int grow = rowBase + wm * 64 + im * 16 + q4 * 4 + r;
            int n = grow & (NN - 1);
            int dp = jf * 16 + r16;          // 0..31
            float x0 = acc[im][jf][r], x1 = acc[im][jf + 2][r];
            float c0 = rcp[n * DD + dp],      s0v = spp[n * DD + dp];
            float c1 = rcp[n * DD + dp + 32], s1v = spp[n * DD + dp + 32];
            float y0 = x0 * c0 - x1 * s0v;
            float y1 = x1 * c1 + x0 * s1v;
            if (isq) { y0 *= QSCALE; y1 *= QSCALE; }
            acc[im][jf][r] = y0;
            acc[im][jf + 2][r] = y1;
          }
    }
  }

  for (int im = 0; im < 4; ++im)
    for (int jf = 0; jf < 4; ++jf)
      for (int r = 0; r < 4; ++r) {
        int grow = rowBase + wm * 64 + im * 16 + q4 * 4 + r;
        int gcol = colBase + wf * 64 + jf * 16 + r16;
        if (BF16OUT)
          ((unsigned short*)Cout)[(size_t)grow * F + gcol] = f2b(acc[im][jf][r]);
        else
          ((float*)Cout)[(size_t)grow * F + gcol] = acc[im][jf][r] + bias[gcol];
      }
}

// ---------- flash attention v7 ----------
// grid: (N/64, B*H) = (32,64) = 2048 blocks. block: 256 (4 waves, 16 q-rows
// each). KV tile 64.
// R3 changes (R2 was grid-limited: 1024 blocks = 16 waves/CU ceiling, occ 37%):
//  * q-tile 128 -> 64 rows: 2048 blocks -> 8 blocks/CU grid ceiling
//    (32 waves/CU). Per-wave state halves (qf/o/s), launch_bounds (256,6).
//    Cost: K/V staging duplicated 2x chip-wide — fine, we're latency-bound.
//  * XCD-aware swizzle: id = x + 32*y; xcd = id&7 (dispatch round-robin),
//    bh = xcd*8 + (slot>>5), qt = slot&31 — all 32 q-tiles of one (b,h) land
//    on ONE XCD -> K/V L2-local (2048 % 8 == 0, bijective).
//  * T5 setprio(1) around QK and PV MFMA clusters (m191: +4-7% attn).
// Carried from R2 (validated):
//  * swapped QK^T (S^T layout) + in-register softmax: cvt_pk_bf16 (RNE) +
//    permlane32_swap + shfl_xor(16)/parity-select redistribution to the PV
//    A-fragment. v_permlane16_swap_b32 FAILED here (R6: 0.9% absmax — its
//    row-pairing differs from assumption); do not reintroduce untested.
//  * l from f32 P, reduced xor16/xor32 in epilogue; Q frags direct from
//    global; LDS = sK+sVT = 16.4 KB.
// NOTE (R5 post-mortem): register-funded cross-iteration pipelining beyond
// the existing 1-deep K/V reg prefetch regressed occupancy — do not re-add.
__global__ __launch_bounds__(256, 6) void attn_k(const unsigned short* __restrict__ qkv,
                                                 unsigned short* __restrict__ obuf) {
  __shared__ alignas(16) unsigned short sK[64 * 64];
  __shared__ alignas(16) unsigned short sVT[64 * 64];

  const int tid = threadIdx.x, lane = tid & 63, wave = tid >> 6;
  const int r16 = lane & 15, q4 = lane >> 4;

  // XCD-aware bijective remap: same-bh blocks -> same XCD
  const int id = blockIdx.x + (int)gridDim.x * blockIdx.y;  // 0..2047
  const int xcd = id & 7, slot = id >> 3;                   // 256 slots/XCD
  const int bh = xcd * 8 + (slot >> 5);                     // 8 bh per XCD
  const int q0 = (slot & 31) * 64;
  const int b = bh >> 4, h = bh & 15;
  const unsigned short* qbase = qkv + (size_t)(b * NN) * F3 + h * DD;

  // Q fragments direct from global (once per block). B-operand layout:
  // lane (r16,q4) holds Q[q=...+r16][d=kk*32+q4*8 .. +7] — plain 16B read.
  bf16x8 qf[2];
#pragma unroll
  for (int kk = 0; kk < 2; ++kk)
    qf[kk] = *(const bf16x8*)(qbase +
        (size_t)(q0 + wave * 16 + r16) * F3 + kk * 32 + q4 * 8);

  const floatx4 z = {0.f, 0.f, 0.f, 0.f};
  floatx4 o[4];
  float lacc = 0.f;
#pragma unroll
  for (int jd = 0; jd < 4; ++jd) o[jd] = z;

  const int krow0 = tid >> 3, kc8 = tid & 7;
  const int vkvp = tid >> 3, vc8 = tid & 7;

  // prefetch t=0 K/V into regs
  const unsigned short* kvb = qbase;
  int4 kreg0 = *(const int4*)(kvb + (size_t)krow0 * F3 + CC + kc8 * 8);
  int4 kreg1 = *(const int4*)(kvb + (size_t)(krow0 + 32) * F3 + CC + kc8 * 8);
  int4 vreg0 = *(const int4*)(kvb + (size_t)(2 * vkvp) * F3 + 2 * CC + vc8 * 8);
  int4 vreg1 = *(const int4*)(kvb + (size_t)(2 * vkvp + 1) * F3 + 2 * CC + vc8 * 8);

  for (int t = 0; t < NN / 64; ++t) {
    __syncthreads();   // previous iter's LDS reads complete

    // stage K_t (swizzled b128) and V_t (transposed, perm-packed b32)
    *(int4*)(&sK[krow0 * 64 + ((kc8 ^ (krow0 & 7)) << 3)]) = kreg0;
    *(int4*)(&sK[(krow0 + 32) * 64 + ((kc8 ^ ((krow0 + 32) & 7)) << 3)]) = kreg1;
    {
      const unsigned* a0 = (const unsigned*)&vreg0;
      const unsigned* a1 = (const unsigned*)&vreg1;
#pragma unroll
      for (int w = 0; w < 4; ++w) {
        unsigned lo = __builtin_amdgcn_perm(a1[w], a0[w], 0x05040100u);
        unsigned hi = __builtin_amdgcn_perm(a1[w], a0[w], 0x07060302u);
        int d0 = vc8 * 8 + 2 * w;
        int sw0 = (2 * w + vc8) & 7;
        int sw1 = (2 * w + 1 + vc8) & 7;
        *(unsigned*)(&sVT[d0 * 64 + (((vkvp >> 2) ^ sw0) << 3) + 2 * (vkvp & 3)]) = lo;
        *(unsigned*)(&sVT[(d0 + 1) * 64 + (((vkvp >> 2) ^ sw1) << 3) + 2 * (vkvp & 3)]) = hi;
      }
    }

    // prefetch t+1 (overlaps compute below)
    if (t + 1 < NN / 64) {
      const unsigned short* nb = qkv + (size_t)(b * NN + (t + 1) * 64) * F3 + h * DD;
      kreg0 = *(const int4*)(nb + (size_t)krow0 * F3 + CC + kc8 * 8);
      kreg1 = *(const int4*)(nb + (size_t)(krow0 + 32) * F3 + CC + kc8 * 8);
      vreg0 = *(const int4*)(nb + (size_t)(2 * vkvp) * F3 + 2 * CC + vc8 * 8);
      vreg1 = *(const int4*)(nb + (size_t)(2 * vkvp + 1) * F3 + 2 * CC + vc8 * 8);
    }

    __syncthreads();   // K_t/V_t visible

    // S^T = K Q^T : lane (r16=q, g=q4) gets P[q][k=jn*16+g*4+r]
    floatx4 s[4];
    __builtin_amdgcn_s_setprio(1);
#pragma unroll
    for (int jn = 0; jn < 4; ++jn) {
      int row = jn * 16 + r16;
      bf16x8 kf0 = *(const bf16x8*)(&sK[row * 64 + ((q4 ^ (row & 7)) << 3)]);
      bf16x8 kf1 = *(const bf16x8*)(&sK[row * 64 + (((4 + q4) ^ (row & 7)) << 3)]);
      floatx4 a = z;
      a = __builtin_amdgcn_mfma_f32_16x16x32_bf16(kf0, qf[0], a, 0, 0, 0);
      a = __builtin_amdgcn_mfma_f32_16x16x32_bf16(kf1, qf[1], a, 0, 0, 0);
      s[jn] = a;
    }
    __builtin_amdgcn_s_setprio(0);

    // P = exp2(S^T); pack to bf16 (RNE) and redistribute in-register.
    // B(j2,g) := pack(P[q][kk*32 + j2*16 + g*4 + 2t], ..+1) held at group g.
    // Need at group g': word t2   = B(g'>>1, 2(g'&1))
    //                   word 2+t2 = B(g'>>1, 2(g'&1)+1)
    // permlane32_swap (x-hi <-> y-lo):
    //   x = {B(0,0),B(0,1),B(1,0),B(1,1)}, y = {B(0,2),B(0,3),B(1,2),B(1,3)}
    // then 16-row exchange via shfl_xor(16) + odd-row select:
    //   x' = odd ? xor16(y) : x  -> {B(0,0),B(0,2),B(1,0),B(1,2)}  (words 0,1)
    //   y' = odd ? y : xor16(x)  -> {B(0,1),B(0,3),B(1,1),B(1,3)}  (words 2,3)
    bf16x8 pf[2];
    const bool oddrow = (q4 & 1) != 0;
#pragma unroll
    for (int kk = 0; kk < 2; ++kk) {
      unsigned bw[2][2];   // [j2 = jn-2kk][t]
#pragma unroll
      for (int j2 = 0; j2 < 2; ++j2) {
        int jn = 2 * kk + j2;
        float p0 = __builtin_amdgcn_exp2f(s[jn][0]);
        float p1 = __builtin_amdgcn_exp2f(s[jn][1]);
        float p2 = __builtin_amdgcn_exp2f(s[jn][2]);
        float p3 = __builtin_amdgcn_exp2f(s[jn][3]);
        lacc += (p0 + p1) + (p2 + p3);
        asm("v_cvt_pk_bf16_f32 %0, %1, %2" : "=v"(bw[j2][0]) : "v"(p0), "v"(p1));
        asm("v_cvt_pk_bf16_f32 %0, %1, %2" : "=v"(bw[j2][1]) : "v"(p2), "v"(p3));
      }
      uintx4 pk;
#pragma unroll
      for (int t2 = 0; t2 < 2; ++t2) {
        unsigned x = bw[0][t2], y = bw[1][t2];
        asm("v_permlane32_swap_b32 %0, %1" : "+v"(x), "+v"(y));
        unsigned xa = (unsigned)__shfl_xor((int)y, 16);
        unsigned ya = (unsigned)__shfl_xor((int)x, 16);
        pk[t2]     = oddrow ? xa : x;
        pk[2 + t2] = oddrow ? y  : ya;
      }
      pf[kk] = __builtin_bit_cast(bf16x8, pk);
    }

    // O += P V
    __builtin_amdgcn_s_setprio(1);
#pragma unroll
    for (int jd = 0; jd < 4; ++jd) {
      int d = jd * 16 + r16;
      int swr = (d + (d >> 3)) & 7;
      bf16x8 vf0 = *(const bf16x8*)(&sVT[d * 64 + ((q4 ^ swr) << 3)]);
      bf16x8 vf1 = *(const bf16x8*)(&sVT[d * 64 + (((4 + q4) ^ swr) << 3)]);
      o[jd] = __builtin_amdgcn_mfma_f32_16x16x32_bf16(pf[0], vf0, o[jd], 0, 0, 0);
      o[jd] = __builtin_amdgcn_mfma_f32_16x16x32_bf16(pf[1], vf1, o[jd], 0, 0, 0);
    }
    __builtin_amdgcn_s_setprio(0);
  }

  // epilogue: l partial over g groups at lanes sharing r16 -> reduce across
  // g (xor 16/32), then shfl-broadcast inv to the o row mapping
  // (o row = q4*4+r; inv for that row lives at lane r16 == q4*4+r).
  float l = lacc;
  l += __shfl_xor(l, 16);
  l += __shfl_xor(l, 32);
  float inv = 1.0f / l;
#pragma unroll
  for (int r = 0; r < 4; ++r) {
    float invr = __shfl(inv, q4 * 4 + r);
    int row = q0 + wave * 16 + q4 * 4 + r;
#pragma unroll
    for (int jd = 0; jd < 4; ++jd) {
      int col = h * DD + jd * 16 + r16;
      obuf[(size_t)(b * NN + row) * CC + col] = f2b(o[jd][r] * invr);
    }
  }
}

// ---------- launcher ----------
extern "C" void kernel_launch(void* const* d_in, const int* in_sizes, int n_in,
                              void* d_out, int out_size, void* d_ws, size_t ws_size,
                              hipStream_t stream) {
  const float* x     = (const float*)d_in[0];
  const float* rc    = (const float*)d_in[1];
  const float* rs    = (const float*)d_in[2];
  const float* wqkv  = (const float*)d_in[3];
  const float* wproj = (const float*)d_in[4];
  const float* bproj = (const float*)d_in[5];
  float* out = (float*)d_out;

  char* w = (char*)d_ws;
  unsigned short* xb     = (unsigned short*)(w);                       // 16,777,216 B
  unsigned short* wqkvb  = (unsigned short*)(w + 16777216);            //  6,291,456 B
  unsigned short* wprojb = (unsigned short*)(w + 23068672);            //  2,097,152 B
  unsigned short* qkvb   = (unsigned short*)(w + 25165824);            // 50,331,648 B
  unsigned short* obuf   = (unsigned short*)(w + 75497472);            // 16,777,216 B

  f32_to_bf16_k<<<(MM * CC / 4 + 255) / 256, 256, 0, stream>>>(x, xb, MM * CC / 4);
  f32_to_bf16_k<<<(F3 * CC / 4 + 255) / 256, 256, 0, stream>>>(wqkv, wqkvb, F3 * CC / 4);
  f32_to_bf16_k<<<(CC * CC / 4 + 255) / 256, 256, 0, stream>>>(wproj, wprojb, CC * CC / 4);

  // GEMM1 with fused RoPE epilogue (rope_k dispatch eliminated)
  gemm_bt<F3, true, true><<<dim3(MM / 128, F3 / 128), 256, 0, stream>>>(
      xb, wqkvb, qkvb, nullptr, rc, rs, CC);

  attn_k<<<dim3(NN / 64, 4 * HH), 256, 0, stream>>>(qkvb, obuf);

  gemm_bt<CC, false, false><<<dim3(MM / 128, CC / 128), 256, 0, stream>>>(
      obuf, wprojb, out, bproj, nullptr, nullptr, CC);
}

// Round 4
// 286.661 us; speedup vs baseline: 1.2124x; 1.2124x over previous
//
#include <hip/hip_runtime.h>

// ---------- constants for this problem ----------
// B=4, N=2048, C=1024, H=16, D=64; M = B*N = 8192
#define MM   8192
#define CC   1024
#define F3   3072
#define NN   2048
#define HH   16
#define DD   64
// q scale: D^-0.5 * log2(e), folded into q during RoPE so softmax uses exp2
#define QSCALE 0.1803368801111731f

typedef __attribute__((ext_vector_type(8))) __bf16 bf16x8;
typedef __attribute__((ext_vector_type(4))) float floatx4;
typedef __attribute__((ext_vector_type(4))) unsigned uintx4;

__device__ __forceinline__ unsigned short f2b(float f) {
  union { float f; unsigned int u; } v; v.f = f;
  unsigned int r = v.u + 0x7fffu + ((v.u >> 16) & 1u);
  return (unsigned short)(r >> 16);
}
__device__ __forceinline__ float b2f(unsigned short b) {
  union { unsigned int u; float f; } v; v.u = ((unsigned int)b) << 16;
  return v.f;
}

// async global->LDS, 16B per lane. LDS dest is wave-uniform base + lane*16,
// so the LDS layout must be lane-linear (no padding) in chunk order.
__device__ __forceinline__ void gl_lds16(const unsigned short* g, unsigned short* l) {
  __builtin_amdgcn_global_load_lds((const __attribute__((address_space(1))) void*)g,
                                   (__attribute__((address_space(3))) void*)l, 16, 0, 0);
}

// ---------- fp32 -> bf16 conversion (vectorized x4) ----------
__global__ __launch_bounds__(256) void f32_to_bf16_k(const float* __restrict__ in,
                                                     unsigned short* __restrict__ out, int n4) {
  int i = blockIdx.x * 256 + threadIdx.x;
  if (i < n4) {
    float4 v = ((const float4*)in)[i];
    ushort4 o;
    o.x = f2b(v.x); o.y = f2b(v.y); o.z = f2b(v.z); o.w = f2b(v.w);
    ((ushort4*)out)[i] = o;
  }
}

// ---------- GEMM: A[M,K] bf16 row-major  x  Bm[F,K] bf16 row-major (B^T layout) ----------
// 128x128 tile, 4 waves (2x2 of 64x64), 16x16x32 bf16 MFMA, BK=32.
// ROPE=true (GEMM1): each wave's 64-col slice is one head; the RoPE pair
// (d, d+32) is acc[im][jf] / acc[im][jf+2] in the SAME lane -> rotate in
// registers on fp32 accumulators, wave-uniform branch on head<32, q scaled.
template <int F, bool BF16OUT, bool ROPE>
__global__ __launch_bounds__(256) void gemm_bt(const unsigned short* __restrict__ A,
                                               const unsigned short* __restrict__ Bm,
                                               void* __restrict__ Cout,
                                               const float* __restrict__ bias,
                                               const float* __restrict__ rcp,
                                               const float* __restrict__ spp, int K) {
  __shared__ alignas(16) unsigned short lA[128 * 32];
  __shared__ alignas(16) unsigned short lB[128 * 32];
  const int tid = threadIdx.x, lane = tid & 63, wave = tid >> 6;
  const int r16 = lane & 15, q4 = lane >> 4;
  const int rowBase = blockIdx.x * 128, colBase = blockIdx.y * 128;
  const int wm = wave & 1, wf = wave >> 1;

  floatx4 acc[4][4];
  const floatx4 z = {0.f, 0.f, 0.f, 0.f};
  for (int i = 0; i < 4; ++i)
    for (int j = 0; j < 4; ++j) acc[i][j] = z;

  for (int k0 = 0; k0 < K; k0 += 32) {
    __syncthreads();
#pragma unroll
    for (int i = 0; i < 2; ++i) {
      int chunk = i * 256 + tid;            // 0..511, 16B each; LDS off = chunk*16B
      int row = chunk >> 2, col = (chunk & 3) * 8;
      gl_lds16(A + (size_t)(rowBase + row) * K + k0 + col, &lA[chunk * 8]);
      gl_lds16(Bm + (size_t)(colBase + row) * K + k0 + col, &lB[chunk * 8]);
    }
    __syncthreads();
    bf16x8 af[4];
    for (int im = 0; im < 4; ++im)
      af[im] = *(const bf16x8*)(&lA[(wm * 64 + im * 16 + r16) * 32 + q4 * 8]);
    for (int jf = 0; jf < 4; ++jf) {
      bf16x8 bfr = *(const bf16x8*)(&lB[(wf * 64 + jf * 16 + r16) * 32 + q4 * 8]);
      for (int im = 0; im < 4; ++im)
        acc[im][jf] = __builtin_amdgcn_mfma_f32_16x16x32_bf16(af[im], bfr, acc[im][jf], 0, 0, 0);
    }
  }

  if (ROPE) {
    int head = (colBase >> 6) + wf;          // 0..47; q:0-15, k:16-31, v:32-47
    if (head < 32) {
      const bool isq = head < 16;
      for (int im = 0; im < 4; ++im)
        for (int jf = 0; jf < 2; ++jf)
          for (int r = 0; r < 4; ++r) {
            int grow = rowBase + wm * 64 + im * 16 + q4 * 4 + r;
            int n = grow & (NN - 1);
            int dp = jf * 16 + r16;          // 0..31
            float x0 = acc[im][jf][r], x1 = acc[im][jf + 2][r];
            float c0 = rcp[n * DD + dp],      s0v = spp[n * DD + dp];
            float c1 = rcp[n * DD + dp + 32], s1v = spp[n * DD + dp + 32];
            float y0 = x0 * c0 - x1 * s0v;
            float y1 = x1 * c1 + x0 * s1v;
            if (isq) { y0 *= QSCALE; y1 *= QSCALE; }
            acc[im][jf][r] = y0;
            acc[im][jf + 2][r] = y1;
          }
    }
  }

  for (int im = 0; im < 4; ++im)
    for (int jf = 0; jf < 4; ++jf)
      for (int r = 0; r < 4; ++r) {
        int grow = rowBase + wm * 64 + im * 16 + q4 * 4 + r;
        int gcol = colBase + wf * 64 + jf * 16 + r16;
        if (BF16OUT)
          ((unsigned short*)Cout)[(size_t)grow * F + gcol] = f2b(acc[im][jf][r]);
        else
          ((float*)Cout)[(size_t)grow * F + gcol] = acc[im][jf][r] + bias[gcol];
      }
}

// ---------- flash attention v8 ----------
// grid: 1024 blocks (XCD-swizzled). block: 256 (4 waves, 32 q-rows each).
// KV tile 64. q-tile 128 (R3's 64-row split REVERTED: it doubled chip-wide
// staging -> bank conflicts exactly 2x, dur 132->160. Kernel is LDS-PIPE
// bound, not occupancy bound — per-q-row DS cycles is the metric to cut).
// R4 change (sigma-trick): PV's k-sum is order-free, so V rows are placed
// PERMUTED in sVT to match P's NATURAL post-QK^T lane layout. A-fragment
// position p = kk*32+g*8+j holds P[q][k(p)], k(p)=kk*32+(j>>2)*16+g*4+(j&3)
// — which lane g already holds in s[2kk+(j>>2)][j&3]. So pf[kk] = the four
// cvt_pk dwords directly; the permlane32_swap + 16 ds_swizzle(shfl_xor) +
// cndmask redistribution is DELETED (-64 DS ops/block-iter, -27% DS cycles).
// V staging stores row-pair m at pair-position P2(m) = bit-permuted index
// (pure address arithmetic, same instruction count, verified by table).
// Carried: XCD swizzle (R3: FETCH 178->34 MB, keep), setprio on MFMA
// clusters, swapped QK^T, cvt_pk RNE softmax, l in f32, Q direct from
// global, LDS 16.4 KB. v_permlane16_swap_b32 remains BANNED (R1: 0.9%
// absmax — gfx950 row-pairing differs from assumption).
// NOTE (R5 post-mortem): register-funded cross-iteration pipelining beyond
// the existing 1-deep K/V reg prefetch regressed occupancy — do not re-add.
__global__ __launch_bounds__(256, 4) void attn_k(const unsigned short* __restrict__ qkv,
                                                 unsigned short* __restrict__ obuf) {
  __shared__ alignas(16) unsigned short sK[64 * 64];
  __shared__ alignas(16) unsigned short sVT[64 * 64];

  const int tid = threadIdx.x, lane = tid & 63, wave = tid >> 6;
  const int r16 = lane & 15, q4 = lane >> 4;

  // XCD-aware bijective remap: all 16 q-tiles of one (b,h) -> same XCD.
  // 1024 blocks, HW round-robins linear id across 8 XCDs.
  const int id = blockIdx.x + (int)gridDim.x * blockIdx.y;  // 0..1023
  const int xcd = id & 7, slot = id >> 3;                   // 128 slots/XCD
  const int bh = xcd * 8 + (slot >> 4);                     // 8 bh per XCD
  const int q0 = (slot & 15) * 128;
  const int b = bh >> 4, h = bh & 15;
  const unsigned short* qbase = qkv + (size_t)(b * NN) * F3 + h * DD;

  // Q fragments direct from global (once per block). B-operand layout:
  // lane (r16,q4) holds Q[q=...+r16][d=kk*32+q4*8 .. +7] — plain 16B read.
  bf16x8 qf[2][2];
#pragma unroll
  for (int im = 0; im < 2; ++im)
#pragma unroll
    for (int kk = 0; kk < 2; ++kk)
      qf[im][kk] = *(const bf16x8*)(qbase +
          (size_t)(q0 + wave * 32 + im * 16 + r16) * F3 + kk * 32 + q4 * 8);

  const floatx4 z = {0.f, 0.f, 0.f, 0.f};
  floatx4 o[2][4];
  float lacc[2] = {0.f, 0.f};
#pragma unroll
  for (int im = 0; im < 2; ++im)
    for (int jd = 0; jd < 4; ++jd) o[im][jd] = z;

  const int krow0 = tid >> 3, kc8 = tid & 7;
  const int vkvp = tid >> 3, vc8 = tid & 7;
  // sigma-trick: pair-position for V row-pair m (m = vkvp):
  // P2 = [m4][m2][m1][m3][m0] (bit permutation, bijective on 0..31)
  const int mp = (vkvp & 16) | ((vkvp & 4) << 1) | ((vkvp & 2) << 1) |
                 ((vkvp & 8) >> 2) | (vkvp & 1);

  // prefetch t=0 K/V into regs
  const unsigned short* kvb = qbase;
  int4 kreg0 = *(const int4*)(kvb + (size_t)krow0 * F3 + CC + kc8 * 8);
  int4 kreg1 = *(const int4*)(kvb + (size_t)(krow0 + 32) * F3 + CC + kc8 * 8);
  int4 vreg0 = *(const int4*)(kvb + (size_t)(2 * vkvp) * F3 + 2 * CC + vc8 * 8);
  int4 vreg1 = *(const int4*)(kvb + (size_t)(2 * vkvp + 1) * F3 + 2 * CC + vc8 * 8);

  for (int t = 0; t < NN / 64; ++t) {
    __syncthreads();   // previous iter's LDS reads complete

    // stage K_t (swizzled b128) and V_t (transposed, perm-packed b32,
    // rows at sigma-permuted positions)
    *(int4*)(&sK[krow0 * 64 + ((kc8 ^ (krow0 & 7)) << 3)]) = kreg0;
    *(int4*)(&sK[(krow0 + 32) * 64 + ((kc8 ^ ((krow0 + 32) & 7)) << 3)]) = kreg1;
    {
      const unsigned* a0 = (const unsigned*)&vreg0;
      const unsigned* a1 = (const unsigned*)&vreg1;
#pragma unroll
      for (int w = 0; w < 4; ++w) {
        unsigned lo = __builtin_amdgcn_perm(a1[w], a0[w], 0x05040100u);
        unsigned hi = __builtin_amdgcn_perm(a1[w], a0[w], 0x07060302u);
        int d0 = vc8 * 8 + 2 * w;
        int sw0 = (2 * w + vc8) & 7;
        int sw1 = (2 * w + 1 + vc8) & 7;
        *(unsigned*)(&sVT[d0 * 64 + (((mp >> 2) ^ sw0) << 3) + 2 * (mp & 3)]) = lo;
        *(unsigned*)(&sVT[(d0 + 1) * 64 + (((mp >> 2) ^ sw1) << 3) + 2 * (mp & 3)]) = hi;
      }
    }

    // prefetch t+1 (overlaps compute below)
    if (t + 1 < NN / 64) {
      const unsigned short* nb = qkv + (size_t)(b * NN + (t + 1) * 64) * F3 + h * DD;
      kreg0 = *(const int4*)(nb + (size_t)krow0 * F3 + CC + kc8 * 8);
      kreg1 = *(const int4*)(nb + (size_t)(krow0 + 32) * F3 + CC + kc8 * 8);
      vreg0 = *(const int4*)(nb + (size_t)(2 * vkvp) * F3 + 2 * CC + vc8 * 8);
      vreg1 = *(const int4*)(nb + (size_t)(2 * vkvp + 1) * F3 + 2 * CC + vc8 * 8);
    }

    __syncthreads();   // K_t/V_t visible

    // S^T = K Q^T : lane (r16=q, g=q4) gets P[q][k=jn*16+g*4+r]
    floatx4 s[2][4];
    __builtin_amdgcn_s_setprio(1);
#pragma unroll
    for (int jn = 0; jn < 4; ++jn) {
      int row = jn * 16 + r16;
      bf16x8 kf0 = *(const bf16x8*)(&sK[row * 64 + ((q4 ^ (row & 7)) << 3)]);
      bf16x8 kf1 = *(const bf16x8*)(&sK[row * 64 + (((4 + q4) ^ (row & 7)) << 3)]);
#pragma unroll
      for (int im = 0; im < 2; ++im) {
        floatx4 a = z;
        a = __builtin_amdgcn_mfma_f32_16x16x32_bf16(kf0, qf[im][0], a, 0, 0, 0);
        a = __builtin_amdgcn_mfma_f32_16x16x32_bf16(kf1, qf[im][1], a, 0, 0, 0);
        s[im][jn] = a;
      }
    }
    __builtin_amdgcn_s_setprio(0);

    // P = exp2(S^T) -> bf16 (RNE cvt_pk). sigma-trick: the 4 packed dwords
    // ARE the PV A-fragment words in order — no cross-lane movement.
    bf16x8 pf[2][2];
#pragma unroll
    for (int im = 0; im < 2; ++im) {
#pragma unroll
      for (int kk = 0; kk < 2; ++kk) {
        uintx4 pk;
#pragma unroll
        for (int j2 = 0; j2 < 2; ++j2) {
          int jn = 2 * kk + j2;
          float p0 = __builtin_amdgcn_exp2f(s[im][jn][0]);
          float p1 = __builtin_amdgcn_exp2f(s[im][jn][1]);
          float p2 = __builtin_amdgcn_exp2f(s[im][jn][2]);
          float p3 = __builtin_amdgcn_exp2f(s[im][jn][3]);
          lacc[im] += (p0 + p1) + (p2 + p3);
          asm("v_cvt_pk_bf16_f32 %0, %1, %2" : "=v"(pk[2 * j2]) : "v"(p0), "v"(p1));
          asm("v_cvt_pk_bf16_f32 %0, %1, %2" : "=v"(pk[2 * j2 + 1]) : "v"(p2), "v"(p3));
        }
        pf[im][kk] = __builtin_bit_cast(bf16x8, pk);
      }
    }

    // O += P V  (V rows sigma-permuted in sVT to match pf's k ordering)
    __builtin_amdgcn_s_setprio(1);
#pragma unroll
    for (int jd = 0; jd < 4; ++jd) {
      int d = jd * 16 + r16;
      int swr = (d + (d >> 3)) & 7;
      bf16x8 vf0 = *(const bf16x8*)(&sVT[d * 64 + ((q4 ^ swr) << 3)]);
      bf16x8 vf1 = *(const bf16x8*)(&sVT[d * 64 + (((4 + q4) ^ swr) << 3)]);
#pragma unroll
      for (int im = 0; im < 2; ++im) {
        o[im][jd] = __builtin_amdgcn_mfma_f32_16x16x32_bf16(pf[im][0], vf0, o[im][jd], 0, 0, 0);
        o[im][jd] = __builtin_amdgcn_mfma_f32_16x16x32_bf16(pf[im][1], vf1, o[im][jd], 0, 0, 0);
      }
    }
    __builtin_amdgcn_s_setprio(0);
  }

  // epilogue: l partial over g groups at lanes sharing r16 -> reduce across
  // g (xor 16/32), then shfl-broadcast inv to the o row mapping
  // (o row = q4*4+r; inv for that row lives at lane r16 == q4*4+r).
#pragma unroll
  for (int im = 0; im < 2; ++im) {
    float l = lacc[im];
    l += __shfl_xor(l, 16);
    l += __shfl_xor(l, 32);
    float inv = 1.0f / l;
#pragma unroll
    for (int r = 0; r < 4; ++r) {
      float invr = __shfl(inv, q4 * 4 + r);
      int row = q0 + wave * 32 + im * 16 + q4 * 4 + r;
#pragma unroll
      for (int jd = 0; jd < 4; ++jd) {
        int col = h * DD + jd * 16 + r16;
        obuf[(size_t)(b * NN + row) * CC + col] = f2b(o[im][jd][r] * invr);
      }
    }
  }
}

// ---------- launcher ----------
extern "C" void kernel_launch(void* const* d_in, const int* in_sizes, int n_in,
                              void* d_out, int out_size, void* d_ws, size_t ws_size,
                              hipStream_t stream) {
  const float* x     = (const float*)d_in[0];
  const float* rc    = (const float*)d_in[1];
  const float* rs    = (const float*)d_in[2];
  const float* wqkv  = (const float*)d_in[3];
  const float* wproj = (const float*)d_in[4];
  const float* bproj = (const float*)d_in[5];
  float* out = (float*)d_out;

  char* w = (char*)d_ws;
  unsigned short* xb     = (unsigned short*)(w);                       // 16,777,216 B
  unsigned short* wqkvb  = (unsigned short*)(w + 16777216);            //  6,291,456 B
  unsigned short* wprojb = (unsigned short*)(w + 23068672);            //  2,097,152 B
  unsigned short* qkvb   = (unsigned short*)(w + 25165824);            // 50,331,648 B
  unsigned short* obuf   = (unsigned short*)(w + 75497472);            // 16,777,216 B

  f32_to_bf16_k<<<(MM * CC / 4 + 255) / 256, 256, 0, stream>>>(x, xb, MM * CC / 4);
  f32_to_bf16_k<<<(F3 * CC / 4 + 255) / 256, 256, 0, stream>>>(wqkv, wqkvb, F3 * CC / 4);
  f32_to_bf16_k<<<(CC * CC / 4 + 255) / 256, 256, 0, stream>>>(wproj, wprojb, CC * CC / 4);

  // GEMM1 with fused RoPE epilogue (rope_k dispatch eliminated)
  gemm_bt<F3, true, true><<<dim3(MM / 128, F3 / 128), 256, 0, stream>>>(
      xb, wqkvb, qkvb, nullptr, rc, rs, CC);

  attn_k<<<dim3(NN / 128, 4 * HH), 256, 0, stream>>>(qkvb, obuf);

  gemm_bt<CC, false, false><<<dim3(MM / 128, CC / 128), 256, 0, stream>>>(
      obuf, wprojb, out, bproj, nullptr, nullptr, CC);
}

// Round 5
// 279.230 us; speedup vs baseline: 1.2446x; 1.0266x over previous
//
#include <hip/hip_runtime.h>

// ---------- constants for this problem ----------
// B=4, N=2048, C=1024, H=16, D=64; M = B*N = 8192
#define MM   8192
#define CC   1024
#define F3   3072
#define NN   2048
#define HH   16
#define DD   64
// q scale: D^-0.5 * log2(e), folded into q during RoPE so softmax uses exp2
#define QSCALE 0.1803368801111731f

typedef __attribute__((ext_vector_type(8))) __bf16 bf16x8;
typedef __attribute__((ext_vector_type(4))) float floatx4;
typedef __attribute__((ext_vector_type(4))) unsigned uintx4;

__device__ __forceinline__ unsigned short f2b(float f) {
  union { float f; unsigned int u; } v; v.f = f;
  unsigned int r = v.u + 0x7fffu + ((v.u >> 16) & 1u);
  return (unsigned short)(r >> 16);
}
__device__ __forceinline__ float b2f(unsigned short b) {
  union { unsigned int u; float f; } v; v.u = ((unsigned int)b) << 16;
  return v.f;
}

// async global->LDS, 16B per lane. LDS dest is wave-uniform base + lane*16,
// so the LDS layout must be lane-linear (no padding) in chunk order.
__device__ __forceinline__ void gl_lds16(const unsigned short* g, unsigned short* l) {
  __builtin_amdgcn_global_load_lds((const __attribute__((address_space(1))) void*)g,
                                   (__attribute__((address_space(3))) void*)l, 16, 0, 0);
}

// ---------- fp32 -> bf16 conversion (vectorized x4) ----------
__global__ __launch_bounds__(256) void f32_to_bf16_k(const float* __restrict__ in,
                                                     unsigned short* __restrict__ out, int n4) {
  int i = blockIdx.x * 256 + threadIdx.x;
  if (i < n4) {
    float4 v = ((const float4*)in)[i];
    ushort4 o;
    o.x = f2b(v.x); o.y = f2b(v.y); o.z = f2b(v.z); o.w = f2b(v.w);
    ((ushort4*)out)[i] = o;
  }
}

// ---------- pipelined GEMM: A[M,K] bf16 rm x Bm[F,K] bf16 rm (B^T layout) ----------
// R5 rewrite (T2+T3+T4+T5 per catalog; replaces 128x128/BK32/2-barrier
// structure that ceilinged at ~580 TF here):
//  * BM=128, BN=256, BK=64; 512 threads = 8 waves as 2M x 4N; per-wave
//    64x64 output (4x4 of 16x16x32 frags) — SAME verified frag algebra as
//    the old kernel, only the LDS geometry changed.
//  * TRIPLE-buffered LDS (3 x 48 KiB = 144 KiB, 1 block/CU): iter t
//    computes tile t from buf[t%3]; then barrier; STAGE(t+3 -> buf[t%3]);
//    vmcnt(12) (= loads of t+2,t+3 in flight; in-order retirement => t+1
//    landed); barrier. WAR safe: overwritten buffer fully read before
//    barrier #1. HBM latency of a stage hides under TWO tile-computes.
//  * RAW s_barrier + explicit counted vmcnt — __syncthreads would make the
//    compiler drain vmcnt(0) at every barrier (the m97 structural stall).
//    sched_barrier(0) after each barrier/wait pins ordering (rule #18).
//  * T2 swizzle via PRE-SWIZZLED GLOBAL SOURCE (m173): gload_lds dest is
//    lane-linear; physical 16B chunk p of row r holds logical chunk
//    p^(r&7). Reads XOR the same way -> 2-way-max bank aliasing (free).
//    Unswizzled BK=64 rows would be a 16-way conflict.
//  * XCD swizzle: 64 row-tiles, 8 per XCD, col-panel walked slowly ->
//    per-XCD L2 set ~2.5 MB (A-stripe 2MB + B-panel 0.5MB) < 4 MB.
//    Grid: GEMM1 768 = 3 exact full rounds; GEMM2 256 = 1 round.
//  * T5 setprio around the MFMA cluster.
// RoPE epilogue ported 1:1 (wave col-slice = one head; wn 0..3).
template <int F, bool BF16OUT, bool ROPE>
__global__ __launch_bounds__(512, 2) void gemm_p(const unsigned short* __restrict__ A,
                                                 const unsigned short* __restrict__ Bm,
                                                 void* __restrict__ Cout,
                                                 const float* __restrict__ bias,
                                                 const float* __restrict__ rcp,
                                                 const float* __restrict__ spp, int K) {
  __shared__ alignas(16) unsigned short lA[3][128 * 64];
  __shared__ alignas(16) unsigned short lB[3][256 * 64];
  const int tid = threadIdx.x, lane = tid & 63, wave = tid >> 6;
  const int r16 = lane & 15, q4 = lane >> 4;
  const int wm = wave & 1, wn = wave >> 1;

  // XCD-aware bijective remap: 8 consecutive-id blocks span 8 XCDs; give
  // each XCD a contiguous 8-row-tile stripe, cols walked slowly.
  const int id = blockIdx.x;
  const int xcd = id & 7, slot = id >> 3;
  const int rx = xcd * 8 + (slot & 7), cy = slot >> 3;
  const int rowBase = rx * 128, colBase = cy * 256;

  // stage-chunk -> global element offset (pre-swizzled source)
  const int cA0 = tid, cA1 = tid + 512;                       // A: 1024 chunks
  const int cB0 = tid, cB1 = tid + 512, cB2 = tid + 1024, cB3 = tid + 1536;  // B: 2048
#define CHOFF(base, c) ((size_t)((base) + ((c) >> 3)) * K + ((((c) & 7) ^ (((c) >> 3) & 7)) << 3))
  const size_t aoff0 = CHOFF(rowBase, cA0), aoff1 = CHOFF(rowBase, cA1);
  const size_t boff0 = CHOFF(colBase, cB0), boff1 = CHOFF(colBase, cB1);
  const size_t boff2 = CHOFF(colBase, cB2), boff3 = CHOFF(colBase, cB3);
#undef CHOFF

#define STAGEP(kt, bsel) do { const int _k0 = (kt) * 64; \
    gl_lds16(A + aoff0 + _k0, &lA[bsel][cA0 * 8]); \
    gl_lds16(A + aoff1 + _k0, &lA[bsel][cA1 * 8]); \
    gl_lds16(Bm + boff0 + _k0, &lB[bsel][cB0 * 8]); \
    gl_lds16(Bm + boff1 + _k0, &lB[bsel][cB1 * 8]); \
    gl_lds16(Bm + boff2 + _k0, &lB[bsel][cB2 * 8]); \
    gl_lds16(Bm + boff3 + _k0, &lB[bsel][cB3 * 8]); } while (0)

  floatx4 acc[4][4];
  const floatx4 z = {0.f, 0.f, 0.f, 0.f};
#pragma unroll
  for (int i = 0; i < 4; ++i)
#pragma unroll
    for (int j = 0; j < 4; ++j) acc[i][j] = z;

  const int nt = K / 64;   // 16

  // prologue: fill the 3-deep pipe
  STAGEP(0, 0);
  STAGEP(1, 1);
  STAGEP(2, 2);
  asm volatile("s_waitcnt vmcnt(12)" ::: "memory");   // tile 0 landed
  __builtin_amdgcn_s_barrier();
  __builtin_amdgcn_sched_barrier(0);

  int bs = 0;
  for (int t = 0; t < nt; ++t) {
    const unsigned short* la = &lA[bs][0];
    const unsigned short* lb = &lB[bs][0];
    bf16x8 af[4][2], bv[4][2];
#pragma unroll
    for (int im = 0; im < 4; ++im) {
      int row = wm * 64 + im * 16 + r16, r7 = row & 7;
      af[im][0] = *(const bf16x8*)(la + row * 64 + ((q4 ^ r7) << 3));
      af[im][1] = *(const bf16x8*)(la + row * 64 + (((4 + q4) ^ r7) << 3));
    }
#pragma unroll
    for (int jf = 0; jf < 4; ++jf) {
      int row = wn * 64 + jf * 16 + r16, r7 = row & 7;
      bv[jf][0] = *(const bf16x8*)(lb + row * 64 + ((q4 ^ r7) << 3));
      bv[jf][1] = *(const bf16x8*)(lb + row * 64 + (((4 + q4) ^ r7) << 3));
    }
    __builtin_amdgcn_s_setprio(1);
#pragma unroll
    for (int jf = 0; jf < 4; ++jf)
#pragma unroll
      for (int im = 0; im < 4; ++im) {
        acc[im][jf] = __builtin_amdgcn_mfma_f32_16x16x32_bf16(af[im][0], bv[jf][0], acc[im][jf], 0, 0, 0);
        acc[im][jf] = __builtin_amdgcn_mfma_f32_16x16x32_bf16(af[im][1], bv[jf][1], acc[im][jf], 0, 0, 0);
      }
    __builtin_amdgcn_s_setprio(0);

    // all waves done READING buf[bs] (ds_reads consumed by MFMAs above)
    __builtin_amdgcn_s_barrier();
    __builtin_amdgcn_sched_barrier(0);
    if (t + 3 < nt) {
      STAGEP(t + 3, bs);     // overwrite just-consumed buffer
      // outstanding: tiles t+2 (<=6, older) + t+3 (6, newer); <=12 left
      // => all of tile t+1 landed (vmcnt retires in order)
      asm volatile("s_waitcnt vmcnt(12)" ::: "memory");
    } else {
      asm volatile("s_waitcnt vmcnt(0)" ::: "memory");
    }
    __builtin_amdgcn_sched_barrier(0);
    __builtin_amdgcn_s_barrier();   // tile t+1 visible to all waves
    __builtin_amdgcn_sched_barrier(0);
    bs = (bs == 2) ? 0 : bs + 1;
  }
#undef STAGEP

  if (ROPE) {
    int head = (colBase >> 6) + wn;          // 0..47; q:0-15, k:16-31, v:32-47
    if (head < 32) {
      const bool isq = head < 16;
#pragma unroll
      for (int im = 0; im < 4; ++im)
#pragma unroll
        for (int jf = 0; jf < 2; ++jf)
#pragma unroll
          for (int r = 0; r < 4; ++r) {
            int grow = rowBase + wm * 64 + im * 16 + q4 * 4 + r;
            int n = grow & (NN - 1);
            int dp = jf * 16 + r16;          // 0..31
            float x0 = acc[im][jf][r], x1 = acc[im][jf + 2][r];
            float c0 = rcp[n * DD + dp],      s0v = spp[n * DD + dp];
            float c1 = rcp[n * DD + dp + 32], s1v = spp[n * DD + dp + 32];
            float y0 = x0 * c0 - x1 * s0v;
            float y1 = x1 * c1 + x0 * s1v;
            if (isq) { y0 *= QSCALE; y1 *= QSCALE; }
            acc[im][jf][r] = y0;
            acc[im][jf + 2][r] = y1;
          }
    }
  }

#pragma unroll
  for (int im = 0; im < 4; ++im)
#pragma unroll
    for (int jf = 0; jf < 4; ++jf)
#pragma unroll
      for (int r = 0; r < 4; ++r) {
        int grow = rowBase + wm * 64 + im * 16 + q4 * 4 + r;
        int gcol = colBase + wn * 64 + jf * 16 + r16;
        if (BF16OUT)
          ((unsigned short*)Cout)[(size_t)grow * F + gcol] = f2b(acc[im][jf][r]);
        else
          ((float*)Cout)[(size_t)grow * F + gcol] = acc[im][jf][r] + bias[gcol];
      }
}

// ---------- flash attention v8 (R4, verified @88us — UNCHANGED) ----------
// grid: 1024 blocks (XCD-swizzled). block: 256 (4 waves, 32 q-rows each).
// KV tile 64. Sigma-trick: V rows placed PERMUTED in sVT so P's natural
// post-QK^T lane layout IS the PV A-fragment (no cross-lane movement).
// v_permlane16_swap_b32 BANNED (R1: row-pairing differs from assumption).
// R3 lesson: do NOT split the q-tile (doubles staging -> LDS-pipe bound).
__global__ __launch_bounds__(256, 4) void attn_k(const unsigned short* __restrict__ qkv,
                                                 unsigned short* __restrict__ obuf) {
  __shared__ alignas(16) unsigned short sK[64 * 64];
  __shared__ alignas(16) unsigned short sVT[64 * 64];

  const int tid = threadIdx.x, lane = tid & 63, wave = tid >> 6;
  const int r16 = lane & 15, q4 = lane >> 4;

  const int id = blockIdx.x + (int)gridDim.x * blockIdx.y;  // 0..1023
  const int xcd = id & 7, slot = id >> 3;                   // 128 slots/XCD
  const int bh = xcd * 8 + (slot >> 4);                     // 8 bh per XCD
  const int q0 = (slot & 15) * 128;
  const int b = bh >> 4, h = bh & 15;
  const unsigned short* qbase = qkv + (size_t)(b * NN) * F3 + h * DD;

  bf16x8 qf[2][2];
#pragma unroll
  for (int im = 0; im < 2; ++im)
#pragma unroll
    for (int kk = 0; kk < 2; ++kk)
      qf[im][kk] = *(const bf16x8*)(qbase +
          (size_t)(q0 + wave * 32 + im * 16 + r16) * F3 + kk * 32 + q4 * 8);

  const floatx4 z = {0.f, 0.f, 0.f, 0.f};
  floatx4 o[2][4];
  float lacc[2] = {0.f, 0.f};
#pragma unroll
  for (int im = 0; im < 2; ++im)
    for (int jd = 0; jd < 4; ++jd) o[im][jd] = z;

  const int krow0 = tid >> 3, kc8 = tid & 7;
  const int vkvp = tid >> 3, vc8 = tid & 7;
  const int mp = (vkvp & 16) | ((vkvp & 4) << 1) | ((vkvp & 2) << 1) |
                 ((vkvp & 8) >> 2) | (vkvp & 1);

  const unsigned short* kvb = qbase;
  int4 kreg0 = *(const int4*)(kvb + (size_t)krow0 * F3 + CC + kc8 * 8);
  int4 kreg1 = *(const int4*)(kvb + (size_t)(krow0 + 32) * F3 + CC + kc8 * 8);
  int4 vreg0 = *(const int4*)(kvb + (size_t)(2 * vkvp) * F3 + 2 * CC + vc8 * 8);
  int4 vreg1 = *(const int4*)(kvb + (size_t)(2 * vkvp + 1) * F3 + 2 * CC + vc8 * 8);

  for (int t = 0; t < NN / 64; ++t) {
    __syncthreads();   // previous iter's LDS reads complete

    *(int4*)(&sK[krow0 * 64 + ((kc8 ^ (krow0 & 7)) << 3)]) = kreg0;
    *(int4*)(&sK[(krow0 + 32) * 64 + ((kc8 ^ ((krow0 + 32) & 7)) << 3)]) = kreg1;
    {
      const unsigned* a0 = (const unsigned*)&vreg0;
      const unsigned* a1 = (const unsigned*)&vreg1;
#pragma unroll
      for (int w = 0; w < 4; ++w) {
        unsigned lo = __builtin_amdgcn_perm(a1[w], a0[w], 0x05040100u);
        unsigned hi = __builtin_amdgcn_perm(a1[w], a0[w], 0x07060302u);
        int d0 = vc8 * 8 + 2 * w;
        int sw0 = (2 * w + vc8) & 7;
        int sw1 = (2 * w + 1 + vc8) & 7;
        *(unsigned*)(&sVT[d0 * 64 + (((mp >> 2) ^ sw0) << 3) + 2 * (mp & 3)]) = lo;
        *(unsigned*)(&sVT[(d0 + 1) * 64 + (((mp >> 2) ^ sw1) << 3) + 2 * (mp & 3)]) = hi;
      }
    }

    if (t + 1 < NN / 64) {
      const unsigned short* nb = qkv + (size_t)(b * NN + (t + 1) * 64) * F3 + h * DD;
      kreg0 = *(const int4*)(nb + (size_t)krow0 * F3 + CC + kc8 * 8);
      kreg1 = *(const int4*)(nb + (size_t)(krow0 + 32) * F3 + CC + kc8 * 8);
      vreg0 = *(const int4*)(nb + (size_t)(2 * vkvp) * F3 + 2 * CC + vc8 * 8);
      vreg1 = *(const int4*)(nb + (size_t)(2 * vkvp + 1) * F3 + 2 * CC + vc8 * 8);
    }

    __syncthreads();   // K_t/V_t visible

    floatx4 s[2][4];
    __builtin_amdgcn_s_setprio(1);
#pragma unroll
    for (int jn = 0; jn < 4; ++jn) {
      int row = jn * 16 + r16;
      bf16x8 kf0 = *(const bf16x8*)(&sK[row * 64 + ((q4 ^ (row & 7)) << 3)]);
      bf16x8 kf1 = *(const bf16x8*)(&sK[row * 64 + (((4 + q4) ^ (row & 7)) << 3)]);
#pragma unroll
      for (int im = 0; im < 2; ++im) {
        floatx4 a = z;
        a = __builtin_amdgcn_mfma_f32_16x16x32_bf16(kf0, qf[im][0], a, 0, 0, 0);
        a = __builtin_amdgcn_mfma_f32_16x16x32_bf16(kf1, qf[im][1], a, 0, 0, 0);
        s[im][jn] = a;
      }
    }
    __builtin_amdgcn_s_setprio(0);

    bf16x8 pf[2][2];
#pragma unroll
    for (int im = 0; im < 2; ++im) {
#pragma unroll
      for (int kk = 0; kk < 2; ++kk) {
        uintx4 pk;
#pragma unroll
        for (int j2 = 0; j2 < 2; ++j2) {
          int jn = 2 * kk + j2;
          float p0 = __builtin_amdgcn_exp2f(s[im][jn][0]);
          float p1 = __builtin_amdgcn_exp2f(s[im][jn][1]);
          float p2 = __builtin_amdgcn_exp2f(s[im][jn][2]);
          float p3 = __builtin_amdgcn_exp2f(s[im][jn][3]);
          lacc[im] += (p0 + p1) + (p2 + p3);
          asm("v_cvt_pk_bf16_f32 %0, %1, %2" : "=v"(pk[2 * j2]) : "v"(p0), "v"(p1));
          asm("v_cvt_pk_bf16_f32 %0, %1, %2" : "=v"(pk[2 * j2 + 1]) : "v"(p2), "v"(p3));
        }
        pf[im][kk] = __builtin_bit_cast(bf16x8, pk);
      }
    }

    __builtin_amdgcn_s_setprio(1);
#pragma unroll
    for (int jd = 0; jd < 4; ++jd) {
      int d = jd * 16 + r16;
      int swr = (d + (d >> 3)) & 7;
      bf16x8 vf0 = *(const bf16x8*)(&sVT[d * 64 + ((q4 ^ swr) << 3)]);
      bf16x8 vf1 = *(const bf16x8*)(&sVT[d * 64 + (((4 + q4) ^ swr) << 3)]);
#pragma unroll
      for (int im = 0; im < 2; ++im) {
        o[im][jd] = __builtin_amdgcn_mfma_f32_16x16x32_bf16(pf[im][0], vf0, o[im][jd], 0, 0, 0);
        o[im][jd] = __builtin_amdgcn_mfma_f32_16x16x32_bf16(pf[im][1], vf1, o[im][jd], 0, 0, 0);
      }
    }
    __builtin_amdgcn_s_setprio(0);
  }

#pragma unroll
  for (int im = 0; im < 2; ++im) {
    float l = lacc[im];
    l += __shfl_xor(l, 16);
    l += __shfl_xor(l, 32);
    float inv = 1.0f / l;
#pragma unroll
    for (int r = 0; r < 4; ++r) {
      float invr = __shfl(inv, q4 * 4 + r);
      int row = q0 + wave * 32 + im * 16 + q4 * 4 + r;
#pragma unroll
      for (int jd = 0; jd < 4; ++jd) {
        int col = h * DD + jd * 16 + r16;
        obuf[(size_t)(b * NN + row) * CC + col] = f2b(o[im][jd][r] * invr);
      }
    }
  }
}

// ---------- launcher ----------
extern "C" void kernel_launch(void* const* d_in, const int* in_sizes, int n_in,
                              void* d_out, int out_size, void* d_ws, size_t ws_size,
                              hipStream_t stream) {
  const float* x     = (const float*)d_in[0];
  const float* rc    = (const float*)d_in[1];
  const float* rs    = (const float*)d_in[2];
  const float* wqkv  = (const float*)d_in[3];
  const float* wproj = (const float*)d_in[4];
  const float* bproj = (const float*)d_in[5];
  float* out = (float*)d_out;

  char* w = (char*)d_ws;
  unsigned short* xb     = (unsigned short*)(w);                       // 16,777,216 B
  unsigned short* wqkvb  = (unsigned short*)(w + 16777216);            //  6,291,456 B
  unsigned short* wprojb = (unsigned short*)(w + 23068672);            //  2,097,152 B
  unsigned short* qkvb   = (unsigned short*)(w + 25165824);            // 50,331,648 B
  unsigned short* obuf   = (unsigned short*)(w + 75497472);            // 16,777,216 B

  f32_to_bf16_k<<<(MM * CC / 4 + 255) / 256, 256, 0, stream>>>(x, xb, MM * CC / 4);
  f32_to_bf16_k<<<(F3 * CC / 4 + 255) / 256, 256, 0, stream>>>(wqkv, wqkvb, F3 * CC / 4);
  f32_to_bf16_k<<<(CC * CC / 4 + 255) / 256, 256, 0, stream>>>(wproj, wprojb, CC * CC / 4);

  // GEMM1 with fused RoPE epilogue: grid 64x12 tiles = 768 = 3 full rounds
  gemm_p<F3, true, true><<<768, 512, 0, stream>>>(
      xb, wqkvb, qkvb, nullptr, rc, rs, CC);

  attn_k<<<dim3(NN / 128, 4 * HH), 256, 0, stream>>>(qkvb, obuf);

  // GEMM2: grid 64x4 = 256 = exactly 1 full round
  gemm_p<CC, false, false><<<256, 512, 0, stream>>>(
      obuf, wprojb, out, bproj, nullptr, nullptr, CC);
}